// Round 3
// baseline (2081.670 us; speedup 1.0000x reference)
//
#include <hip/hip_runtime.h>
#include <hip/hip_bf16.h>

#define DEVFN __device__ __forceinline__

// Problem constants
constexpr int B   = 4096;
constexpr int ENC = 168;
constexpr int DEC = 24;
constexpr int H   = 64;
constexpr int G   = 4 * H;   // 256 gates
constexpr int IN  = 20;      // 1 + 5 + 3 + 4 + 7
constexpr int BT  = 8;       // batch tile per block
constexpr int NBLK = B / BT; // 512 blocks -> 2 per CU

// Workspace (float) layout: K-major transposed weights + fused biases + misc
constexpr int W0IH = 0;              // [IN][G]
constexpr int W0HH = W0IH + IN * G;  // [H][G]
constexpr int B0   = W0HH + H * G;   // [G]
constexpr int W1IH = B0 + G;         // [H][G]
constexpr int W1HH = W1IH + H * G;   // [H][G]
constexpr int B1   = W1HH + H * G;   // [G]
constexpr int WDIH = B1 + G;         // [IN][G]
constexpr int WDHH = WDIH + IN * G;  // [H][G]
constexpr int BD   = WDHH + H * G;   // [G]
constexpr int WOUT = BD + G;         // [H]
constexpr int BOUT = WOUT + H;       // [1]
constexpr int EMB  = BOUT + 1;       // 574 concat embeddings
constexpr int EMB_HOUR = 0;          // 24*5 = 120
constexpr int EMB_WD   = 120;        // 8*3  = 24
constexpr int EMB_MO   = 144;        // 13*4 = 52
constexpr int EMB_WOY  = 196;        // 54*7 = 378
constexpr int NEMB = 574;
constexpr int WS_FLOATS = EMB + NEMB;

DEVFN float sigm(float x) {
    x = fminf(fmaxf(x, -30.f), 30.f);
    return 1.f / (1.f + __expf(-x));
}
DEVFN float tanh_(float x) {
    x = fminf(fmaxf(x, -15.f), 15.f);
    const float e = __expf(2.f * x);
    return (e - 1.f) / (e + 1.f);
}

// ---------------- prep: f32 weights -> f32 transposed (K-major) in ws ------
__global__ void prep_kernel(
    const float* __restrict__ w0ih, const float* __restrict__ w0hh,
    const float* __restrict__ b0ih, const float* __restrict__ b0hh,
    const float* __restrict__ w1ih, const float* __restrict__ w1hh,
    const float* __restrict__ b1ih, const float* __restrict__ b1hh,
    const float* __restrict__ wdih, const float* __restrict__ wdhh,
    const float* __restrict__ bdih, const float* __restrict__ bdhh,
    const float* __restrict__ wout, const float* __restrict__ boutp,
    const float* __restrict__ eh,   const float* __restrict__ ewd,
    const float* __restrict__ emo,  const float* __restrict__ ewoy,
    float* __restrict__ ws)
{
    for (int idx = blockIdx.x * blockDim.x + threadIdx.x; idx < WS_FLOATS;
         idx += gridDim.x * blockDim.x) {
        float v;
        if (idx < W0HH)      { int j = idx - W0IH; v = w0ih[(j % G) * IN + j / G]; }
        else if (idx < B0)   { int j = idx - W0HH; v = w0hh[(j % G) * H  + j / G]; }
        else if (idx < W1IH) { int r = idx - B0;   v = b0ih[r] + b0hh[r]; }
        else if (idx < W1HH) { int j = idx - W1IH; v = w1ih[(j % G) * H  + j / G]; }
        else if (idx < B1)   { int j = idx - W1HH; v = w1hh[(j % G) * H  + j / G]; }
        else if (idx < WDIH) { int r = idx - B1;   v = b1ih[r] + b1hh[r]; }
        else if (idx < WDHH) { int j = idx - WDIH; v = wdih[(j % G) * IN + j / G]; }
        else if (idx < BD)   { int j = idx - WDHH; v = wdhh[(j % G) * H  + j / G]; }
        else if (idx < WOUT) { int r = idx - BD;   v = bdih[r] + bdhh[r]; }
        else if (idx < BOUT) { v = wout[idx - WOUT]; }
        else if (idx < EMB)  { v = boutp[0]; }
        else {
            int j = idx - EMB;
            if (j < 120)      v = eh[j];
            else if (j < 144) v = ewd[j - 120];
            else if (j < 196) v = emo[j - 144];
            else              v = ewoy[j - 196];
        }
        ws[idx] = v;
    }
}

// ---------------- gate GEMM: thread r computes gate row r for BT batches ---
template <int KX>
DEVFN void gate_gemm(const float* __restrict__ wx, const float (*__restrict__ sx)[BT],
                     const float* __restrict__ wh, const float (*__restrict__ sh)[BT],
                     const float* __restrict__ bp, float* __restrict__ sg, int r)
{
    float acc[BT];
    const float bias = bp[r];
#pragma unroll
    for (int b = 0; b < BT; b++) acc[b] = bias;

#pragma unroll 10
    for (int k = 0; k < KX; k++) {
        const float w = wx[k * G + r];
        const float4 a = *(const float4*)&sx[k][0];
        const float4 c = *(const float4*)&sx[k][4];
        acc[0] = fmaf(w, a.x, acc[0]); acc[1] = fmaf(w, a.y, acc[1]);
        acc[2] = fmaf(w, a.z, acc[2]); acc[3] = fmaf(w, a.w, acc[3]);
        acc[4] = fmaf(w, c.x, acc[4]); acc[5] = fmaf(w, c.y, acc[5]);
        acc[6] = fmaf(w, c.z, acc[6]); acc[7] = fmaf(w, c.w, acc[7]);
    }
#pragma unroll 16
    for (int k = 0; k < H; k++) {
        const float w = wh[k * G + r];
        const float4 a = *(const float4*)&sh[k][0];
        const float4 c = *(const float4*)&sh[k][4];
        acc[0] = fmaf(w, a.x, acc[0]); acc[1] = fmaf(w, a.y, acc[1]);
        acc[2] = fmaf(w, a.z, acc[2]); acc[3] = fmaf(w, a.w, acc[3]);
        acc[4] = fmaf(w, c.x, acc[4]); acc[5] = fmaf(w, c.y, acc[5]);
        acc[6] = fmaf(w, c.z, acc[6]); acc[7] = fmaf(w, c.w, acc[7]);
    }
#pragma unroll
    for (int b = 0; b < BT; b++) sg[b * G + r] = acc[b];
}

// ------------- LSTM cell elementwise: 512 units, thread t does u=t, t+256 --
DEVFN void cell_update(const float* __restrict__ sg, float (*__restrict__ sh)[BT],
                       float& ca, float& cb, int tid)
{
#pragma unroll
    for (int p = 0; p < 2; p++) {
        const int u = tid + p * 256;
        const int b = u >> 6, j = u & 63;
        const float gi = sg[b * G + j];
        const float gf = sg[b * G + 64 + j];
        const float gg = sg[b * G + 128 + j];
        const float go = sg[b * G + 192 + j];
        float c = p ? cb : ca;
        c = sigm(gf) * c + sigm(gi) * tanh_(gg);
        const float h = sigm(go) * tanh_(c);
        if (p) cb = c; else ca = c;
        sh[j][b] = h;
    }
}

// ---------------- main persistent kernel: 1 block = BT batches, all steps --
__global__ __launch_bounds__(256, 2) void lstm_kernel(
    const int* __restrict__ input_time, const float* __restrict__ label_p,
    const int* __restrict__ decoder_time, const float* __restrict__ ws,
    float* __restrict__ out)
{
    __shared__ __align__(16) float s_x[IN][BT];
    __shared__ __align__(16) float s_h0[H][BT];
    __shared__ __align__(16) float s_h1[H][BT];
    __shared__ __align__(16) float s_g[BT * G];
    __shared__ float s_emb[NEMB];
    __shared__ float s_wout[H];
    __shared__ float s_prev[BT];
    __shared__ float s_bout;

    const int tid = threadIdx.x;
    const int b0g = blockIdx.x * BT;

    for (int i = tid; i < NEMB; i += 256) s_emb[i] = ws[EMB + i];
    if (tid < H) s_wout[tid] = ws[WOUT + tid];
    if (tid == 0) s_bout = ws[BOUT];
    if (tid < BT) s_prev[tid] = label_p[(b0g + tid) * ENC + (ENC - 1)];
    for (int i = tid; i < H * BT; i += 256) {
        ((float*)s_h0)[i] = 0.f;
        ((float*)s_h1)[i] = 0.f;
    }
    float c0a = 0.f, c0b = 0.f, c1a = 0.f, c1b = 0.f;
    __syncthreads();

    // ---------------- encoder: fused layer0+layer1, 168 steps ----------------
    for (int t = 0; t < ENC; ++t) {
        if (tid < IN * BT) {
            const int b = tid & (BT - 1), k = tid >> 3;
            const int bg = b0g + b;
            float v;
            if (k == 0) {
                v = label_p[bg * ENC + t];   // input_q = label_p (ref ignores input_p_q)
            } else {
                const int f = k - 1;
                const int* it = input_time + (bg * ENC + t) * 4;
                if (f < 5)       v = s_emb[EMB_HOUR + it[0] * 5 + f];
                else if (f < 8)  v = s_emb[EMB_WD   + it[1] * 3 + (f - 5)];
                else if (f < 12) v = s_emb[EMB_MO   + it[2] * 4 + (f - 8)];
                else             v = s_emb[EMB_WOY  + it[3] * 7 + (f - 12)];
            }
            s_x[k][b] = v;
        }
        __syncthreads();

        gate_gemm<IN>(ws + W0IH, s_x, ws + W0HH, s_h0, ws + B0, s_g, tid);
        __syncthreads();
        cell_update(s_g, s_h0, c0a, c0b, tid);
        __syncthreads();

        gate_gemm<H>(ws + W1IH, s_h0, ws + W1HH, s_h1, ws + B1, s_g, tid);
        __syncthreads();
        cell_update(s_g, s_h1, c1a, c1b, tid);
        __syncthreads();
    }

    // ---------------- decoder: 24 autoregressive steps -----------------------
    for (int t = 0; t < DEC; ++t) {
        if (tid < IN * BT) {
            const int b = tid & (BT - 1), k = tid >> 3;
            const int bg = b0g + b;
            float v;
            if (k == 0) {
                v = s_prev[b];
            } else {
                const int f = k - 1;
                const int* it = decoder_time + (bg * DEC + t) * 4;
                if (f < 5)       v = s_emb[EMB_HOUR + it[0] * 5 + f];
                else if (f < 8)  v = s_emb[EMB_WD   + it[1] * 3 + (f - 5)];
                else if (f < 12) v = s_emb[EMB_MO   + it[2] * 4 + (f - 8)];
                else             v = s_emb[EMB_WOY  + it[3] * 7 + (f - 12)];
            }
            s_x[k][b] = v;
        }
        __syncthreads();

        gate_gemm<IN>(ws + WDIH, s_x, ws + WDHH, s_h1, ws + BD, s_g, tid);
        __syncthreads();
        cell_update(s_g, s_h1, c1a, c1b, tid);
        __syncthreads();

        if (tid < BT) {
            const int b = tid;
            float acc = s_bout;
#pragma unroll 16
            for (int j = 0; j < H; j++) acc = fmaf(s_wout[j], s_h1[j][b], acc);
            out[(b0g + b) * DEC + t] = acc;   // fp32 output per reference dtype
            s_prev[b] = acc;                  // carry fp32 prev, matching reference
        }
        __syncthreads();
    }
}

extern "C" void kernel_launch(void* const* d_in, const int* in_sizes, int n_in,
                              void* d_out, int out_size, void* d_ws, size_t ws_size,
                              hipStream_t stream)
{
    typedef const float* fp;
    const int* input_time   = (const int*)d_in[1];
    fp         label_p      = (fp)d_in[2];
    const int* decoder_time = (const int*)d_in[3];
    float*     ws           = (float*)d_ws;

    prep_kernel<<<80, 256, 0, stream>>>(
        (fp)d_in[4],  (fp)d_in[5],  (fp)d_in[6],  (fp)d_in[7],
        (fp)d_in[8],  (fp)d_in[9],  (fp)d_in[10], (fp)d_in[11],
        (fp)d_in[12], (fp)d_in[13], (fp)d_in[14], (fp)d_in[15],
        (fp)d_in[16], (fp)d_in[17],
        (fp)d_in[18], (fp)d_in[19], (fp)d_in[20], (fp)d_in[21],
        ws);

    lstm_kernel<<<NBLK, 256, 0, stream>>>(
        input_time, label_p, decoder_time, ws, (float*)d_out);
}

// Round 4
// 469.569 us; speedup vs baseline: 4.4331x; 4.4331x over previous
//
#include <hip/hip_runtime.h>

#define DEVFN __device__ __forceinline__

typedef float  f32x4  __attribute__((ext_vector_type(4)));
typedef short  bf16x8 __attribute__((ext_vector_type(8)));

// Problem constants
constexpr int ENC = 168;
constexpr int DEC = 24;
constexpr int BT  = 16;            // batch tile (MFMA M)
constexpr int NBLK = 4096 / BT;    // 256 blocks -> 1 per CU

// Workspace layout. ushort region: weight fragments, [c][tt16][s][lane64][j8]
constexpr int W0F = 0;             // 3*16*2*512 = 49152 ushorts (K=96: x20+h64+pad)
constexpr int W1F = 49152;         // 4*16*2*512 = 65536          (K=128: h0 + h1)
constexpr int WDF = 114688;        // 3*16*2*512 = 49152          (K=96: xin20+h64+pad)
// float region (float indices; starts at byte 327680 = float 81920)
constexpr int F_B0   = 81920;      // fused bias l0 [256]
constexpr int F_B1   = 82176;
constexpr int F_BD   = 82432;
constexpr int F_WOUT = 82688;      // [64]
constexpr int F_BOUT = 82752;      // [1]
constexpr int F_EMB  = 82753;      // [574] hour120 wd24 mo52 woy378
constexpr int NEMB = 574;

DEVFN ushort f2bf(float v) {       // fp32 -> bf16 bits, RNE
    unsigned b = __float_as_uint(v);
    return (ushort)((b + 0x7FFFu + ((b >> 16) & 1u)) >> 16);
}
DEVFN float bf2f(ushort u) { return __uint_as_float(((unsigned)u) << 16); }
DEVFN float sigm(float x)  { return __builtin_amdgcn_rcpf(1.f + __expf(-x)); }
DEVFN float tanhv(float x) { return fmaf(2.f, sigm(x + x), -1.f); }

// ---------------- prep: weights -> bf16 hi/lo MFMA-B fragments + fp32 tail --
__global__ void prep_kernel(
    const float* __restrict__ w0ih, const float* __restrict__ w0hh,
    const float* __restrict__ b0ih, const float* __restrict__ b0hh,
    const float* __restrict__ w1ih, const float* __restrict__ w1hh,
    const float* __restrict__ b1ih, const float* __restrict__ b1hh,
    const float* __restrict__ wdih, const float* __restrict__ wdhh,
    const float* __restrict__ bdih, const float* __restrict__ bdhh,
    const float* __restrict__ wout, const float* __restrict__ boutp,
    const float* __restrict__ eh,   const float* __restrict__ ewd,
    const float* __restrict__ emo,  const float* __restrict__ ewoy,
    void* __restrict__ ws)
{
    ushort* wsu = (ushort*)ws;
    float*  wsf = (float*)ws;
    const int total = 81920 + 1471;   // hi/lo pair elements + fp32 tail
    for (int idx = blockIdx.x * blockDim.x + threadIdx.x; idx < total;
         idx += gridDim.x * blockDim.x) {
        if (idx < 81920) {
            int layer, q, base;
            if (idx < 24576)      { layer = 0; q = idx;         base = W0F; }
            else if (idx < 57344) { layer = 1; q = idx - 24576; base = W1F; }
            else                  { layer = 2; q = idx - 57344; base = WDF; }
            // q = (c*16+tt)*512 + l*8 + j
            int c  = q >> 13;         // 16*512
            int rem = q & 8191;
            int tt = rem >> 9;
            int r2 = rem & 511;
            int l  = r2 >> 3, j = r2 & 7;
            int k  = c * 32 + (l >> 4) * 8 + j;   // B-frag: k = quad*8 + elem
            int n  = tt * 16 + (l & 15);          // B-frag: n = lane&15
            float v = 0.f;
            if (layer == 0) {
                if (k < 20) v = w0ih[n * 20 + k];
                else if (k < 84) v = w0hh[n * 64 + (k - 20)];
            } else if (layer == 1) {
                if (k < 64) v = w1ih[n * 64 + k];
                else        v = w1hh[n * 64 + (k - 64)];
            } else {
                if (k < 20) v = wdih[n * 20 + k];
                else if (k < 84) v = wdhh[n * 64 + (k - 20)];
            }
            ushort hi = f2bf(v);
            ushort lo = f2bf(v - bf2f(hi));
            int o = base + ((c * 16 + tt) * 2 + 0) * 512 + l * 8 + j;
            wsu[o]       = hi;
            wsu[o + 512] = lo;     // s-stride = 512 ushorts
        } else {
            int f = idx - 81920;
            float v;
            if (f < 256)      v = b0ih[f] + b0hh[f];
            else if (f < 512) v = b1ih[f - 256] + b1hh[f - 256];
            else if (f < 768) v = bdih[f - 512] + bdhh[f - 512];
            else if (f < 832) v = wout[f - 768];
            else if (f == 832) v = boutp[0];
            else {
                int e = f - 833;
                if (e < 120)      v = eh[e];
                else if (e < 144) v = ewd[e - 120];
                else if (e < 196) v = emo[e - 144];
                else              v = ewoy[e - 196];
            }
            wsf[81920 + f] = v;
        }
    }
}

// write fp32 h into A-frag LDS (hi+lo bf16) at K-index k, row m
DEVFN void write_h(ushort* buf, int k, int m, float h) {
    int c = k >> 5, qq = (k >> 3) & 3, e = k & 7, lane = m + qq * 16;
    ushort hi = f2bf(h);
    buf[(c * 2 + 0) * 512 + lane * 8 + e] = hi;
    buf[(c * 2 + 1) * 512 + lane * 8 + e] = f2bf(h - bf2f(hi));
}

// build the 20 input features for one step into A0 chunk-0 region
DEVFN void build_x(int tid, int b0g, const float* s_emb, const float* s_prev,
                   const float* lp, const int* tim, int t, int seqlen, bool dec,
                   ushort* A0f) {
    int b = tid & 15, bg = b0g + b;
#pragma unroll
    for (int h2 = 0; h2 < 2; h2++) {
        int k = (tid >> 4) + h2 * 16;
        if (k < 20) {
            float v;
            if (k == 0) v = dec ? s_prev[b] : lp[bg * ENC + t];
            else {
                int f = k - 1;
                const int* itp = tim + (bg * seqlen + t) * 4;
                if (f < 5)       v = s_emb[itp[0] * 5 + f];
                else if (f < 8)  v = s_emb[120 + itp[1] * 3 + (f - 5)];
                else if (f < 12) v = s_emb[144 + itp[2] * 4 + (f - 8)];
                else             v = s_emb[196 + itp[3] * 7 + (f - 12)];
            }
            int qq = k >> 3, e = k & 7, lane = b + qq * 16;
            ushort hi = f2bf(v);
            A0f[lane * 8 + e]       = hi;
            A0f[512 + lane * 8 + e] = f2bf(v - bf2f(hi));
        }
    }
}

#define MFMA3(ACC, AH, AL, BH, BL)                                         \
    ACC = __builtin_amdgcn_mfma_f32_16x16x32_bf16(AH, BH, ACC, 0, 0, 0);   \
    ACC = __builtin_amdgcn_mfma_f32_16x16x32_bf16(AL, BH, ACC, 0, 0, 0);   \
    ACC = __builtin_amdgcn_mfma_f32_16x16x32_bf16(AH, BL, ACC, 0, 0, 0);

// ---------------- main persistent MFMA kernel ------------------------------
__global__ __launch_bounds__(256, 1) void lstm_mfma(
    const int* __restrict__ input_time, const float* __restrict__ label_p,
    const int* __restrict__ decoder_time, const void* __restrict__ ws,
    float* __restrict__ out)
{
    const ushort* wsu = (const ushort*)ws;
    const float*  wsf = (const float*)ws;

    __shared__ __align__(16) ushort A0f[3 * 2 * 512];  // [c][s][lane][8] bf16
    __shared__ __align__(16) ushort A1f[4 * 2 * 512];
    __shared__ float s_emb[NEMB];
    __shared__ float s_wout[64];
    __shared__ float sh1[64 * 17];                      // [j][m], padded
    __shared__ float s_prev[16];
    __shared__ float s_bout;

    const int tid = threadIdx.x;
    const int w   = tid >> 6;         // wave 0..3
    const int l   = tid & 63;
    const int m16 = l & 15;
    const int q   = l >> 4;
    const int b0g = blockIdx.x * BT;
    const int j   = w * 16 + m16;     // unit index this lane's C covers

    // ---- init LDS ----
    for (int i = tid; i < NEMB; i += 256) s_emb[i] = wsf[F_EMB + i];
    if (tid < 64) s_wout[tid] = wsf[F_WOUT + tid];
    if (tid == 0) s_bout = wsf[F_BOUT];
    if (tid < 16) s_prev[tid] = label_p[(b0g + tid) * ENC + (ENC - 1)];
    for (int i = tid; i < 3 * 2 * 512; i += 256) A0f[i] = 0;
    for (int i = tid; i < 4 * 2 * 512; i += 256) A1f[i] = 0;

    // ---- persistent weight fragments in registers ----
    bf16x8 w0f[3][4][2];   // [chunk][gate-tile][hi/lo]; tt = t*4 + w
    bf16x8 w1f[4][4][2];
#pragma unroll
    for (int c = 0; c < 3; c++)
#pragma unroll
        for (int t = 0; t < 4; t++)
#pragma unroll
            for (int s = 0; s < 2; s++)
                w0f[c][t][s] = *(const bf16x8*)(wsu + W0F +
                    ((c * 16 + (t * 4 + w)) * 2 + s) * 512 + l * 8);
#pragma unroll
    for (int c = 0; c < 4; c++)
#pragma unroll
        for (int t = 0; t < 4; t++)
#pragma unroll
            for (int s = 0; s < 2; s++)
                w1f[c][t][s] = *(const bf16x8*)(wsu + W1F +
                    ((c * 16 + (t * 4 + w)) * 2 + s) * 512 + l * 8);
    float bias0[4], bias1[4];
#pragma unroll
    for (int t = 0; t < 4; t++) {
        bias0[t] = wsf[F_B0 + t * 64 + j];
        bias1[t] = wsf[F_B1 + t * 64 + j];
    }
    float c0s[4] = {0.f, 0.f, 0.f, 0.f};
    float c1s[4] = {0.f, 0.f, 0.f, 0.f};

    __syncthreads();
    build_x(tid, b0g, s_emb, s_prev, label_p, input_time, 0, ENC, false, A0f);
    __syncthreads();

    // ================= encoder: 168 fused 2-layer steps =================
    for (int t = 0; t < ENC; ++t) {
        const bool last = (t == ENC - 1);
        // load A0 fragments (all waves need full X)
        bf16x8 a0h[3], a0l[3];
#pragma unroll
        for (int c = 0; c < 3; c++) {
            a0h[c] = *(const bf16x8*)(A0f + (c * 2 + 0) * 512 + l * 8);
            a0l[c] = *(const bf16x8*)(A0f + (c * 2 + 1) * 512 + l * 8);
        }
        __syncthreads();   // all A0 reads done -> A0 writes below are safe

        f32x4 acc[4];
#pragma unroll
        for (int t4 = 0; t4 < 4; t4++) acc[t4] = f32x4{bias0[t4], bias0[t4], bias0[t4], bias0[t4]};
#pragma unroll
        for (int c = 0; c < 3; c++)
#pragma unroll
            for (int t4 = 0; t4 < 4; t4++) {
                MFMA3(acc[t4], a0h[c], a0l[c], w0f[c][t4][0], w0f[c][t4][1]);
            }

        if (t + 1 < ENC)
            build_x(tid, b0g, s_emb, s_prev, label_p, input_time, t + 1, ENC, false, A0f);

        // layer0 cell: lane-local (m = q*4+r, unit j)
#pragma unroll
        for (int r = 0; r < 4; r++) {
            float cc = sigm(acc[1][r]) * c0s[r] + sigm(acc[0][r]) * tanhv(acc[2][r]);
            c0s[r] = cc;
            float hh = sigm(acc[3][r]) * tanhv(cc);
            int m = q * 4 + r;
            write_h(A1f, j, m, hh);                 // layer1 input k=j
            if (!last) write_h(A0f, 20 + j, m, hh); // layer0 recurrent k=20+j
        }
        __syncthreads();   // h0 visible

        bf16x8 a1h[4], a1l[4];
#pragma unroll
        for (int c = 0; c < 4; c++) {
            a1h[c] = *(const bf16x8*)(A1f + (c * 2 + 0) * 512 + l * 8);
            a1l[c] = *(const bf16x8*)(A1f + (c * 2 + 1) * 512 + l * 8);
        }
        __syncthreads();   // all A1 reads done -> h1 writes safe

        f32x4 acc1[4];
#pragma unroll
        for (int t4 = 0; t4 < 4; t4++) acc1[t4] = f32x4{bias1[t4], bias1[t4], bias1[t4], bias1[t4]};
#pragma unroll
        for (int c = 0; c < 4; c++)
#pragma unroll
            for (int t4 = 0; t4 < 4; t4++) {
                MFMA3(acc1[t4], a1h[c], a1l[c], w1f[c][t4][0], w1f[c][t4][1]);
            }
#pragma unroll
        for (int r = 0; r < 4; r++) {
            float cc = sigm(acc1[1][r]) * c1s[r] + sigm(acc1[0][r]) * tanhv(acc1[2][r]);
            c1s[r] = cc;
            float hh = sigm(acc1[3][r]) * tanhv(cc);
            int m = q * 4 + r;
            if (!last) write_h(A1f, 64 + j, m, hh); // layer1 recurrent
            else       write_h(A0f, 20 + j, m, hh); // hand h1 to decoder slot
        }
        __syncthreads();
    }

    // ================= decoder: 24 autoregressive steps =================
    // reload w0f/bias0 with decoder weights (same fragment shape)
#pragma unroll
    for (int c = 0; c < 3; c++)
#pragma unroll
        for (int t = 0; t < 4; t++)
#pragma unroll
            for (int s = 0; s < 2; s++)
                w0f[c][t][s] = *(const bf16x8*)(wsu + WDF +
                    ((c * 16 + (t * 4 + w)) * 2 + s) * 512 + l * 8);
#pragma unroll
    for (int t = 0; t < 4; t++) bias0[t] = wsf[F_BD + t * 64 + j];

    for (int t = 0; t < DEC; ++t) {
        build_x(tid, b0g, s_emb, s_prev, label_p, decoder_time, t, DEC, true, A0f);
        __syncthreads();   // x visible

        bf16x8 a0h[3], a0l[3];
#pragma unroll
        for (int c = 0; c < 3; c++) {
            a0h[c] = *(const bf16x8*)(A0f + (c * 2 + 0) * 512 + l * 8);
            a0l[c] = *(const bf16x8*)(A0f + (c * 2 + 1) * 512 + l * 8);
        }
        __syncthreads();   // reads done -> h1 writes safe

        f32x4 acc[4];
#pragma unroll
        for (int t4 = 0; t4 < 4; t4++) acc[t4] = f32x4{bias0[t4], bias0[t4], bias0[t4], bias0[t4]};
#pragma unroll
        for (int c = 0; c < 3; c++)
#pragma unroll
            for (int t4 = 0; t4 < 4; t4++) {
                MFMA3(acc[t4], a0h[c], a0l[c], w0f[c][t4][0], w0f[c][t4][1]);
            }
#pragma unroll
        for (int r = 0; r < 4; r++) {
            float cc = sigm(acc[1][r]) * c1s[r] + sigm(acc[0][r]) * tanhv(acc[2][r]);
            c1s[r] = cc;
            float hh = sigm(acc[3][r]) * tanhv(cc);
            int m = q * 4 + r;
            write_h(A0f, 20 + j, m, hh);     // recurrent for next dec step
            sh1[j * 17 + m] = hh;            // fp32 copy for output head
        }
        __syncthreads();   // sh1 visible

        if (tid < 16) {
            int m = tid;
            float a = s_bout;
#pragma unroll
            for (int jj = 0; jj < 64; jj++) a = fmaf(s_wout[jj], sh1[jj * 17 + m], a);
            out[(b0g + m) * DEC + t] = a;
            s_prev[m] = a;                   // autoregressive carry (fp32)
        }
        __syncthreads();
    }
}

extern "C" void kernel_launch(void* const* d_in, const int* in_sizes, int n_in,
                              void* d_out, int out_size, void* d_ws, size_t ws_size,
                              hipStream_t stream)
{
    typedef const float* fp;
    const int* input_time   = (const int*)d_in[1];
    fp         label_p      = (fp)d_in[2];
    const int* decoder_time = (const int*)d_in[3];

    prep_kernel<<<128, 256, 0, stream>>>(
        (fp)d_in[4],  (fp)d_in[5],  (fp)d_in[6],  (fp)d_in[7],
        (fp)d_in[8],  (fp)d_in[9],  (fp)d_in[10], (fp)d_in[11],
        (fp)d_in[12], (fp)d_in[13], (fp)d_in[14], (fp)d_in[15],
        (fp)d_in[16], (fp)d_in[17],
        (fp)d_in[18], (fp)d_in[19], (fp)d_in[20], (fp)d_in[21],
        d_ws);

    lstm_mfma<<<NBLK, 256, 0, stream>>>(
        input_time, label_p, decoder_time, d_ws, (float*)d_out);
}

// Round 5
// 440.275 us; speedup vs baseline: 4.7281x; 1.0665x over previous
//
#include <hip/hip_runtime.h>

#define DEVFN __device__ __forceinline__

typedef float  f32x4  __attribute__((ext_vector_type(4)));
typedef short  bf16x8 __attribute__((ext_vector_type(8)));

// Problem constants
constexpr int ENC = 168;
constexpr int DEC = 24;
constexpr int BT  = 16;            // batch tile (MFMA M)
constexpr int NBLK = 4096 / BT;    // 256 blocks -> 1 per CU (512 thr = 2 waves/SIMD)

// Workspace layout (same as round 4). ushort region: [c][tt16][s][lane64][j8]
constexpr int W0F = 0;             // 3*16*2*512 ushorts (K=96: x20+h64+pad)
constexpr int W1F = 49152;         // 4*16*2*512          (K=128: h0 + h1)
constexpr int WDF = 114688;        // 3*16*2*512          (K=96: xin20+h64+pad)
constexpr int F_B0   = 81920;      // float indices
constexpr int F_B1   = 82176;
constexpr int F_BD   = 82432;
constexpr int F_WOUT = 82688;
constexpr int F_BOUT = 82752;
constexpr int F_EMB  = 82753;      // [574] hour120 wd24 mo52 woy378
constexpr int NEMB = 574;

DEVFN ushort f2bf(float v) {       // fp32 -> bf16 bits, RNE
    unsigned b = __float_as_uint(v);
    return (ushort)((b + 0x7FFFu + ((b >> 16) & 1u)) >> 16);
}
DEVFN float bf2f(ushort u) { return __uint_as_float(((unsigned)u) << 16); }
DEVFN float sigm(float x)  { return __builtin_amdgcn_rcpf(1.f + __expf(-x)); }
DEVFN float tanhv(float x) { return fmaf(2.f, sigm(x + x), -1.f); }

// ---------------- prep: weights -> bf16 hi/lo MFMA-B fragments + fp32 tail --
__global__ void prep_kernel(
    const float* __restrict__ w0ih, const float* __restrict__ w0hh,
    const float* __restrict__ b0ih, const float* __restrict__ b0hh,
    const float* __restrict__ w1ih, const float* __restrict__ w1hh,
    const float* __restrict__ b1ih, const float* __restrict__ b1hh,
    const float* __restrict__ wdih, const float* __restrict__ wdhh,
    const float* __restrict__ bdih, const float* __restrict__ bdhh,
    const float* __restrict__ wout, const float* __restrict__ boutp,
    const float* __restrict__ eh,   const float* __restrict__ ewd,
    const float* __restrict__ emo,  const float* __restrict__ ewoy,
    void* __restrict__ ws)
{
    ushort* wsu = (ushort*)ws;
    float*  wsf = (float*)ws;
    const int total = 81920 + 1471;
    for (int idx = blockIdx.x * blockDim.x + threadIdx.x; idx < total;
         idx += gridDim.x * blockDim.x) {
        if (idx < 81920) {
            int layer, q, base;
            if (idx < 24576)      { layer = 0; q = idx;         base = W0F; }
            else if (idx < 57344) { layer = 1; q = idx - 24576; base = W1F; }
            else                  { layer = 2; q = idx - 57344; base = WDF; }
            int c  = q >> 13;
            int rem = q & 8191;
            int tt = rem >> 9;
            int r2 = rem & 511;
            int l  = r2 >> 3, j = r2 & 7;
            int k  = c * 32 + (l >> 4) * 8 + j;   // B-frag: k = quad*8 + elem
            int n  = tt * 16 + (l & 15);          // B-frag: n = lane&15 (gate row)
            float v = 0.f;
            if (layer == 0) {
                if (k < 20) v = w0ih[n * 20 + k];
                else if (k < 84) v = w0hh[n * 64 + (k - 20)];
            } else if (layer == 1) {
                if (k < 64) v = w1ih[n * 64 + k];
                else        v = w1hh[n * 64 + (k - 64)];
            } else {
                if (k < 20) v = wdih[n * 20 + k];
                else if (k < 84) v = wdhh[n * 64 + (k - 20)];
            }
            ushort hi = f2bf(v);
            ushort lo = f2bf(v - bf2f(hi));
            int o = base + ((c * 16 + tt) * 2 + 0) * 512 + l * 8 + j;
            wsu[o]       = hi;
            wsu[o + 512] = lo;
        } else {
            int f = idx - 81920;
            float v;
            if (f < 256)      v = b0ih[f] + b0hh[f];
            else if (f < 512) v = b1ih[f - 256] + b1hh[f - 256];
            else if (f < 768) v = bdih[f - 512] + bdhh[f - 512];
            else if (f < 832) v = wout[f - 768];
            else if (f == 832) v = boutp[0];
            else {
                int e = f - 833;
                if (e < 120)      v = eh[e];
                else if (e < 144) v = ewd[e - 120];
                else if (e < 196) v = emo[e - 144];
                else              v = ewoy[e - 196];
            }
            wsf[81920 + f] = v;
        }
    }
}

DEVFN float emb_lookup(const float* s_emb, int kk, int idx) {
    int f = kk - 1;
    if (f < 5)  return s_emb[idx * 5 + f];
    if (f < 8)  return s_emb[120 + idx * 3 + (f - 5)];
    if (f < 12) return s_emb[144 + idx * 4 + (f - 8)];
    return s_emb[196 + idx * 7 + (f - 12)];
}

// store fp32 value as hi/lo bf16 into A chunk0 at K-index kk, row mm
DEVFN void store_xv(ushort* A, int kk, int mm, float v) {
    int q = kk >> 3, e = kk & 7, lane = mm + 16 * q;
    ushort hi = f2bf(v);
    A[lane * 8 + e]       = hi;
    A[512 + lane * 8 + e] = f2bf(v - bf2f(hi));
}

DEVFN void store_h(ushort* A, int off, float h) {
    ushort hi = f2bf(h);
    A[off]       = hi;
    A[off + 512] = f2bf(h - bf2f(hi));
}

#define MFMA3(ACC, AH, AL, BH, BL)                                         \
    ACC = __builtin_amdgcn_mfma_f32_16x16x32_bf16(AH, BH, ACC, 0, 0, 0);   \
    ACC = __builtin_amdgcn_mfma_f32_16x16x32_bf16(AL, BH, ACC, 0, 0, 0);   \
    ACC = __builtin_amdgcn_mfma_f32_16x16x32_bf16(AH, BL, ACC, 0, 0, 0);

// ---------------- main persistent MFMA kernel: 512 thr, 8 waves ------------
__global__ __launch_bounds__(512, 2) void lstm_mfma(
    const int* __restrict__ input_time, const float* __restrict__ label_p,
    const int* __restrict__ decoder_time, const void* __restrict__ ws,
    float* __restrict__ out)
{
    const ushort* wsu = (const ushort*)ws;
    const float*  wsf = (const float*)ws;

    // A: 7 chunks (0-2: layer0/dec K=96; 3-6: layer1 K=128) x hi/lo x 512
    __shared__ __align__(16) ushort A[7 * 2 * 512];
    __shared__ float g0[4 * 64 * 19];   // gate buf layer0 [gamma][u][m pad19]
    __shared__ float g1[4 * 64 * 19];   // gate buf layer1/decoder
    __shared__ float s_emb[NEMB];
    __shared__ float s_wout[64];
    __shared__ float sh1[64 * 17];
    __shared__ float s_bout;

    const int tid = threadIdx.x;
    const int w   = tid >> 6;          // wave 0..7
    const int l   = tid & 63;
    const int b0g = blockIdx.x * BT;

    // ---- phase 1 init ----
    for (int i = tid; i < 7 * 2 * 512; i += 512) A[i] = 0;
    for (int i = tid; i < NEMB; i += 512) s_emb[i] = wsf[F_EMB + i];
    if (tid < 64) s_wout[tid] = wsf[F_WOUT + tid];
    if (tid == 0) s_bout = wsf[F_BOUT];

    // ---- per-wave weight fragments: gate-tiles 2w, 2w+1 ----
    bf16x8 w0f[3][2][2], w1f[4][2][2];
#pragma unroll
    for (int c = 0; c < 3; c++)
#pragma unroll
        for (int p = 0; p < 2; p++)
#pragma unroll
            for (int s = 0; s < 2; s++)
                w0f[c][p][s] = *(const bf16x8*)(wsu + W0F +
                    ((c * 16 + (2 * w + p)) * 2 + s) * 512 + l * 8);
#pragma unroll
    for (int c = 0; c < 4; c++)
#pragma unroll
        for (int p = 0; p < 2; p++)
#pragma unroll
            for (int s = 0; s < 2; s++)
                w1f[c][p][s] = *(const bf16x8*)(wsu + W1F +
                    ((c * 16 + (2 * w + p)) * 2 + s) * 512 + l * 8);
    float bias0[2], bias1[2];
    int goff[2];
#pragma unroll
    for (int p = 0; p < 2; p++) {
        int n = (2 * w + p) * 16 + (l & 15);
        bias0[p] = wsf[F_B0 + n];
        bias1[p] = wsf[F_B1 + n];
        goff[p]  = (n >> 6) * 1216 + (n & 63) * 19 + ((l >> 4) << 2);
    }

    // ---- cell ownership: thread owns units cu, batches cm0, cm0+1 ----
    const int cu  = tid >> 3;          // 0..63
    const int cm0 = (tid & 7) * 2;     // 0..14
    int offL1in[2], offRec[2], offL1rec[2];
#pragma unroll
    for (int cc = 0; cc < 2; cc++) {
        int m = cm0 + cc;
        { int k = cu,      c = 3 + (k >> 5), k32 = k & 31;
          offL1in[cc]  = (c * 2) * 512 + (m + 16 * (k32 >> 3)) * 8 + (k32 & 7); }
        { int k = 20 + cu, c = k >> 5,       k32 = k & 31;
          offRec[cc]   = (c * 2) * 512 + (m + 16 * (k32 >> 3)) * 8 + (k32 & 7); }
        { int k = 64 + cu, c = 3 + (k >> 5), k32 = k & 31;
          offL1rec[cc] = (c * 2) * 512 + (m + 16 * (k32 >> 3)) * 8 + (k32 & 7); }
    }
    float c0s[2] = {0.f, 0.f}, c1s[2] = {0.f, 0.f};

    // ---- build-x thread roles: 320 threads = 20 features x 16 batches ----
    const int kk = tid >> 4, mm = tid & 15;
    const bool bx = tid < 320;
    const int sel = (kk <= 5) ? 0 : (kk <= 8) ? 1 : (kk <= 12) ? 2 : 3;

    __syncthreads();
    // build x(0)
    if (bx) {
        float v = (kk == 0) ? label_p[(b0g + mm) * ENC]
                : emb_lookup(s_emb, kk, input_time[((b0g + mm) * ENC) * 4 + sel]);
        store_xv(A, kk, mm, v);
    }
    __syncthreads();

    // ============ encoder: fused pipeline, iter i = layer0(i) + layer1(i-1) ==
    for (int i = 0; i <= ENC; ++i) {
        const bool L0 = (i < ENC), L1 = (i >= 1);
        // prefetch globals for x(i+1)
        float pre_f = 0.f; int pre_i = 0;
        const bool doX = (i + 1 < ENC) && bx;
        if (doX) {
            if (kk == 0) pre_f = label_p[(b0g + mm) * ENC + (i + 1)];
            else         pre_i = input_time[((b0g + mm) * ENC + (i + 1)) * 4 + sel];
        }
        bf16x8 a0h[3], a0l[3], a1h[4], a1l[4];
        if (L0) {
#pragma unroll
            for (int c = 0; c < 3; c++) {
                a0h[c] = *(const bf16x8*)(A + (c * 2) * 512 + l * 8);
                a0l[c] = *(const bf16x8*)(A + (c * 2 + 1) * 512 + l * 8);
            }
        }
        if (L1) {
#pragma unroll
            for (int c = 0; c < 4; c++) {
                a1h[c] = *(const bf16x8*)(A + ((3 + c) * 2) * 512 + l * 8);
                a1l[c] = *(const bf16x8*)(A + ((3 + c) * 2 + 1) * 512 + l * 8);
            }
        }
        f32x4 acc0[2], acc1[2];
        if (L0) {
#pragma unroll
            for (int p = 0; p < 2; p++) acc0[p] = f32x4{bias0[p], bias0[p], bias0[p], bias0[p]};
#pragma unroll
            for (int c = 0; c < 3; c++)
#pragma unroll
                for (int p = 0; p < 2; p++) { MFMA3(acc0[p], a0h[c], a0l[c], w0f[c][p][0], w0f[c][p][1]); }
        }
        if (L1) {
#pragma unroll
            for (int p = 0; p < 2; p++) acc1[p] = f32x4{bias1[p], bias1[p], bias1[p], bias1[p]};
#pragma unroll
            for (int c = 0; c < 4; c++)
#pragma unroll
                for (int p = 0; p < 2; p++) { MFMA3(acc1[p], a1h[c], a1l[c], w1f[c][p][0], w1f[c][p][1]); }
        }
        if (L0) {
#pragma unroll
            for (int p = 0; p < 2; p++)
#pragma unroll
                for (int r = 0; r < 4; r++) g0[goff[p] + r] = acc0[p][r];
        }
        if (L1) {
#pragma unroll
            for (int p = 0; p < 2; p++)
#pragma unroll
                for (int r = 0; r < 4; r++) g1[goff[p] + r] = acc1[p][r];
        }
        __syncthreads();

        // cell updates (thread-owned c-state), h -> A for next iteration
        if (L0) {
#pragma unroll
            for (int cc = 0; cc < 2; cc++) {
                const int m = cm0 + cc;
                const float gi = g0[cu * 19 + m];
                const float gf = g0[1216 + cu * 19 + m];
                const float gg = g0[2432 + cu * 19 + m];
                const float go = g0[3648 + cu * 19 + m];
                float c = sigm(gf) * c0s[cc] + sigm(gi) * tanhv(gg);
                c0s[cc] = c;
                float h = sigm(go) * tanhv(c);
                store_h(A, offL1in[cc], h);   // layer1 input k=u
                store_h(A, offRec[cc], h);    // layer0 recurrent k=20+u
            }
        }
        if (L1) {
#pragma unroll
            for (int cc = 0; cc < 2; cc++) {
                const int m = cm0 + cc;
                const float gi = g1[cu * 19 + m];
                const float gf = g1[1216 + cu * 19 + m];
                const float gg = g1[2432 + cu * 19 + m];
                const float go = g1[3648 + cu * 19 + m];
                float c = sigm(gf) * c1s[cc] + sigm(gi) * tanhv(gg);
                c1s[cc] = c;
                float h = sigm(go) * tanhv(c);
                // i<ENC: layer1 recurrent k=64+u ; i==ENC: decoder h slot k=20+u
                store_h(A, (i < ENC) ? offL1rec[cc] : offRec[cc], h);
            }
        }
        if (doX)
            store_xv(A, kk, mm, (kk == 0) ? pre_f : emb_lookup(s_emb, kk, pre_i));
        __syncthreads();
    }

    // ============ encoder->decoder transition ============
#pragma unroll
    for (int c = 0; c < 3; c++)
#pragma unroll
        for (int p = 0; p < 2; p++)
#pragma unroll
            for (int s = 0; s < 2; s++)
                w0f[c][p][s] = *(const bf16x8*)(wsu + WDF +
                    ((c * 16 + (2 * w + p)) * 2 + s) * 512 + l * 8);
#pragma unroll
    for (int p = 0; p < 2; p++) bias0[p] = wsf[F_BD + (2 * w + p) * 16 + (l & 15)];

    if (bx && kk >= 1)
        store_xv(A, kk, mm, emb_lookup(s_emb, kk,
                 decoder_time[((b0g + mm) * DEC) * 4 + sel]));
    if (tid < 16)
        store_xv(A, 0, tid, label_p[(b0g + tid) * ENC + (ENC - 1)]);
    __syncthreads();

    // ============ decoder: 24 autoregressive steps ============
    for (int t = 0; t < DEC; ++t) {
        int pre_i = 0;
        const bool doX = (t + 1 < DEC) && bx && (kk >= 1);
        if (doX) pre_i = decoder_time[((b0g + mm) * DEC + (t + 1)) * 4 + sel];

        bf16x8 ah[3], al[3];
#pragma unroll
        for (int c = 0; c < 3; c++) {
            ah[c] = *(const bf16x8*)(A + (c * 2) * 512 + l * 8);
            al[c] = *(const bf16x8*)(A + (c * 2 + 1) * 512 + l * 8);
        }
        f32x4 acc[2];
#pragma unroll
        for (int p = 0; p < 2; p++) acc[p] = f32x4{bias0[p], bias0[p], bias0[p], bias0[p]};
#pragma unroll
        for (int c = 0; c < 3; c++)
#pragma unroll
            for (int p = 0; p < 2; p++) { MFMA3(acc[p], ah[c], al[c], w0f[c][p][0], w0f[c][p][1]); }
#pragma unroll
        for (int p = 0; p < 2; p++)
#pragma unroll
            for (int r = 0; r < 4; r++) g1[goff[p] + r] = acc[p][r];
        __syncthreads();

#pragma unroll
        for (int cc = 0; cc < 2; cc++) {
            const int m = cm0 + cc;
            const float gi = g1[cu * 19 + m];
            const float gf = g1[1216 + cu * 19 + m];
            const float gg = g1[2432 + cu * 19 + m];
            const float go = g1[3648 + cu * 19 + m];
            float c = sigm(gf) * c1s[cc] + sigm(gi) * tanhv(gg);
            c1s[cc] = c;
            float h = sigm(go) * tanhv(c);
            store_h(A, offRec[cc], h);     // recurrent k=20+u for next step
            sh1[cu * 17 + m] = h;          // fp32 for output head
        }
        if (doX) store_xv(A, kk, mm, emb_lookup(s_emb, kk, pre_i));
        __syncthreads();

        if (tid < 16) {
            float a = s_bout;
#pragma unroll
            for (int u = 0; u < 64; u++) a = fmaf(s_wout[u], sh1[u * 17 + tid], a);
            out[(b0g + tid) * DEC + t] = a;
            if (t + 1 < DEC) store_xv(A, 0, tid, a);   // autoregressive prev
        }
        __syncthreads();
    }
}

extern "C" void kernel_launch(void* const* d_in, const int* in_sizes, int n_in,
                              void* d_out, int out_size, void* d_ws, size_t ws_size,
                              hipStream_t stream)
{
    typedef const float* fp;
    const int* input_time   = (const int*)d_in[1];
    fp         label_p      = (fp)d_in[2];
    const int* decoder_time = (const int*)d_in[3];

    prep_kernel<<<128, 256, 0, stream>>>(
        (fp)d_in[4],  (fp)d_in[5],  (fp)d_in[6],  (fp)d_in[7],
        (fp)d_in[8],  (fp)d_in[9],  (fp)d_in[10], (fp)d_in[11],
        (fp)d_in[12], (fp)d_in[13], (fp)d_in[14], (fp)d_in[15],
        (fp)d_in[16], (fp)d_in[17],
        (fp)d_in[18], (fp)d_in[19], (fp)d_in[20], (fp)d_in[21],
        d_ws);

    lstm_mfma<<<NBLK, 512, 0, stream>>>(
        input_time, label_p, decoder_time, d_ws, (float*)d_out);
}

// Round 6
// 419.385 us; speedup vs baseline: 4.9636x; 1.0498x over previous
//
#include <hip/hip_runtime.h>

#define DEVFN __device__ __forceinline__

typedef float  f32x4  __attribute__((ext_vector_type(4)));
typedef short  bf16x8 __attribute__((ext_vector_type(8)));

// Problem constants
constexpr int ENC = 168;
constexpr int DEC = 24;
constexpr int BT  = 16;            // batch tile (MFMA N now)
constexpr int NBLK = 4096 / BT;    // 256 blocks -> 1 per CU

// Workspace layout (identical to rounds 4/5). ushort region: [c][tt16][s][lane64][j8]
constexpr int W0F = 0;             // 3*16*2*512 ushorts (K=96: x20+h64+pad)
constexpr int W1F = 49152;         // 4*16*2*512          (K=128: h0 + h1)
constexpr int WDF = 114688;        // 3*16*2*512          (K=96: xin20+h64+pad)
constexpr int F_B0   = 81920;      // float indices
constexpr int F_B1   = 82176;
constexpr int F_BD   = 82432;
constexpr int F_WOUT = 82688;
constexpr int F_BOUT = 82752;
constexpr int F_EMB  = 82753;      // [574] hour120 wd24 mo52 woy378
constexpr int NEMB = 574;

DEVFN ushort f2bf(float v) {       // fp32 -> bf16 bits, RNE
    unsigned b = __float_as_uint(v);
    return (ushort)((b + 0x7FFFu + ((b >> 16) & 1u)) >> 16);
}
DEVFN float bf2f(ushort u) { return __uint_as_float(((unsigned)u) << 16); }
DEVFN float sigm(float x)  { return __builtin_amdgcn_rcpf(1.f + __expf(-x)); }
DEVFN float tanhv(float x) { return fmaf(2.f, sigm(x + x), -1.f); }

// ---------------- prep: weights -> bf16 hi/lo MFMA fragments + fp32 tail ---
// Fragment mapping: within tile tt, gate row n = tt*16 + (l&15), k = c*32 + (l>>4)*8 + j.
// Works as A-operand (row=lane&15) or B-operand (col=lane&15) unchanged.
__global__ void prep_kernel(
    const float* __restrict__ w0ih, const float* __restrict__ w0hh,
    const float* __restrict__ b0ih, const float* __restrict__ b0hh,
    const float* __restrict__ w1ih, const float* __restrict__ w1hh,
    const float* __restrict__ b1ih, const float* __restrict__ b1hh,
    const float* __restrict__ wdih, const float* __restrict__ wdhh,
    const float* __restrict__ bdih, const float* __restrict__ bdhh,
    const float* __restrict__ wout, const float* __restrict__ boutp,
    const float* __restrict__ eh,   const float* __restrict__ ewd,
    const float* __restrict__ emo,  const float* __restrict__ ewoy,
    void* __restrict__ ws)
{
    ushort* wsu = (ushort*)ws;
    float*  wsf = (float*)ws;
    const int total = 81920 + 1471;
    for (int idx = blockIdx.x * blockDim.x + threadIdx.x; idx < total;
         idx += gridDim.x * blockDim.x) {
        if (idx < 81920) {
            int layer, q, base;
            if (idx < 24576)      { layer = 0; q = idx;         base = W0F; }
            else if (idx < 57344) { layer = 1; q = idx - 24576; base = W1F; }
            else                  { layer = 2; q = idx - 57344; base = WDF; }
            int c  = q >> 13;
            int rem = q & 8191;
            int tt = rem >> 9;
            int r2 = rem & 511;
            int l  = r2 >> 3, j = r2 & 7;
            int k  = c * 32 + (l >> 4) * 8 + j;
            int n  = tt * 16 + (l & 15);
            float v = 0.f;
            if (layer == 0) {
                if (k < 20) v = w0ih[n * 20 + k];
                else if (k < 84) v = w0hh[n * 64 + (k - 20)];
            } else if (layer == 1) {
                if (k < 64) v = w1ih[n * 64 + k];
                else        v = w1hh[n * 64 + (k - 64)];
            } else {
                if (k < 20) v = wdih[n * 20 + k];
                else if (k < 84) v = wdhh[n * 64 + (k - 20)];
            }
            ushort hi = f2bf(v);
            ushort lo = f2bf(v - bf2f(hi));
            int o = base + ((c * 16 + tt) * 2 + 0) * 512 + l * 8 + j;
            wsu[o]       = hi;
            wsu[o + 512] = lo;
        } else {
            int f = idx - 81920;
            float v;
            if (f < 256)      v = b0ih[f] + b0hh[f];
            else if (f < 512) v = b1ih[f - 256] + b1hh[f - 256];
            else if (f < 768) v = bdih[f - 512] + bdhh[f - 512];
            else if (f < 832) v = wout[f - 768];
            else if (f == 832) v = boutp[0];
            else {
                int e = f - 833;
                if (e < 120)      v = eh[e];
                else if (e < 144) v = ewd[e - 120];
                else if (e < 196) v = emo[e - 144];
                else              v = ewoy[e - 196];
            }
            wsf[81920 + f] = v;
        }
    }
}

DEVFN float emb_lookup(const float* s_emb, int kk, int idx) {
    int f = kk - 1;
    if (f < 5)  return s_emb[idx * 5 + f];
    if (f < 8)  return s_emb[120 + idx * 3 + (f - 5)];
    if (f < 12) return s_emb[144 + idx * 4 + (f - 8)];
    return s_emb[196 + idx * 7 + (f - 12)];
}

// activation-fragment offsets (ushort index; hi plane, lo at +512)
DEVFN int offC0(int k, int m) {            // chunks 0-2 space, k in [0,96)
    int c = k >> 5, k32 = k & 31;
    return (c * 2) * 512 + (m + 16 * (k32 >> 3)) * 8 + (k32 & 7);
}
DEVFN int offC3(int k, int m) {            // chunks 3-6 space, k in [0,128)
    int c = 3 + (k >> 5), k32 = k & 31;
    return (c * 2) * 512 + (m + 16 * (k32 >> 3)) * 8 + (k32 & 7);
}
DEVFN void store_h(ushort* A, int off, float h) {
    ushort hi = f2bf(h);
    A[off]       = hi;
    A[off + 512] = f2bf(h - bf2f(hi));
}

// 3-term fp32-accurate product: (Wh+Wl)(Ah+Al) ~= Wh*Ah + Wl*Ah + Wh*Al
#define MFMA3(ACC, WH, WL, AH, AL)                                         \
    ACC = __builtin_amdgcn_mfma_f32_16x16x32_bf16(WH, AH, ACC, 0, 0, 0);   \
    ACC = __builtin_amdgcn_mfma_f32_16x16x32_bf16(WL, AH, ACC, 0, 0, 0);   \
    ACC = __builtin_amdgcn_mfma_f32_16x16x32_bf16(WH, AL, ACC, 0, 0, 0);

// ---------------- main persistent MFMA kernel: 512 thr ---------------------
// Waves 0-3: layer0 (encoder). Waves 4-7: layer1 (encoder) then decoder.
// Wave w computes gate tiles {gamma*4 + (w&3)}: lane (q,m) owns all 4 gates of
// units u0..u0+3 (u0=(w&3)*16+q*4) for batch m -> lane-local cell update.
__global__ __launch_bounds__(512, 2) void lstm_mfma(
    const int* __restrict__ input_time, const float* __restrict__ label_p,
    const int* __restrict__ decoder_time, const void* __restrict__ ws,
    float* __restrict__ out)
{
    const ushort* wsu = (const ushort*)ws;
    const float*  wsf = (const float*)ws;

    // double-buffered activation fragments: 7 chunks x hi/lo x 512 ushorts
    __shared__ __align__(16) ushort Abuf[2][7 * 2 * 512];
    __shared__ float s_emb[NEMB];
    __shared__ float s_wout[64];
    __shared__ float sh1[16 * 68];     // [m][u] padded
    __shared__ float s_bout;

    const int tid = threadIdx.x;
    const int w   = tid >> 6;          // wave 0..7
    const int l   = tid & 63;
    const int q   = l >> 4;
    const int m   = l & 15;
    const int wl  = w & 3;
    const bool isL0 = (w < 4);
    const int b0g = blockIdx.x * BT;
    const int u0  = wl * 16 + q * 4;   // this lane's 4 units

    // ---- init ----
    for (int i = tid; i < 2 * 7 * 2 * 512; i += 512) ((ushort*)Abuf)[i] = 0;
    for (int i = tid; i < NEMB; i += 512) s_emb[i] = wsf[F_EMB + i];
    if (tid < 64) s_wout[tid] = wsf[F_WOUT + tid];
    if (tid == 0) s_bout = wsf[F_BOUT];

    // ---- weight fragments (A-operand), persistent in registers ----
    bf16x8 wA[4][4][2];                // [chunk][gamma][hi/lo]
    if (isL0) {
#pragma unroll
        for (int c = 0; c < 3; c++)
#pragma unroll
            for (int g = 0; g < 4; g++)
#pragma unroll
                for (int s = 0; s < 2; s++)
                    wA[c][g][s] = *(const bf16x8*)(wsu + W0F +
                        ((c * 16 + (g * 4 + wl)) * 2 + s) * 512 + l * 8);
    } else {
#pragma unroll
        for (int c = 0; c < 4; c++)
#pragma unroll
            for (int g = 0; g < 4; g++)
#pragma unroll
                for (int s = 0; s < 2; s++)
                    wA[c][g][s] = *(const bf16x8*)(wsu + W1F +
                        ((c * 16 + (g * 4 + wl)) * 2 + s) * 512 + l * 8);
    }
    f32x4 biasv[4];
#pragma unroll
    for (int g = 0; g < 4; g++)
        biasv[g] = *(const f32x4*)(wsf + (isL0 ? F_B0 : F_B1) + g * 64 + u0);

    float cst[4] = {0.f, 0.f, 0.f, 0.f};

    // x-build roles: 320 threads = 20 features x 16 batches
    const int kk = tid >> 4, mm = tid & 15;
    const bool bx = (tid < 320);
    const int sel = (kk <= 5) ? 0 : (kk <= 8) ? 1 : (kk <= 12) ? 2 : 3;

    __syncthreads();
    if (bx) {    // x(0) into Abuf[0]
        float v = (kk == 0) ? label_p[(b0g + mm) * ENC]
                : emb_lookup(s_emb, kk, input_time[((b0g + mm) * ENC) * 4 + sel]);
        store_h(Abuf[0], offC0(kk, mm), v);
    }
    __syncthreads();

    // ============ encoder pipeline: iter i = layer0(i) + layer1(i-1) ========
    for (int i = 0; i <= ENC; ++i) {
        const ushort* Ar = Abuf[i & 1];
        ushort* Aw = Abuf[(i + 1) & 1];
        const bool active = isL0 ? (i < ENC) : (i >= 1);

        // prefetch globals for next x
        float pre_f = 0.f; int pre_i = 0;
        const bool encX  = (i + 1 < ENC) && bx;
        const bool decX0 = (i == ENC) && bx;
        if (encX) {
            if (kk == 0) pre_f = label_p[(b0g + mm) * ENC + (i + 1)];
            else         pre_i = input_time[((b0g + mm) * ENC + (i + 1)) * 4 + sel];
        } else if (decX0) {
            if (kk == 0) pre_f = label_p[(b0g + mm) * ENC + (ENC - 1)];
            else         pre_i = decoder_time[((b0g + mm) * DEC) * 4 + sel];
        }

        if (active) {
            f32x4 acc[4];
#pragma unroll
            for (int g = 0; g < 4; g++) acc[g] = biasv[g];
            if (isL0) {
                bf16x8 ah[3], al[3];
#pragma unroll
                for (int c = 0; c < 3; c++) {
                    ah[c] = *(const bf16x8*)(Ar + (c * 2) * 512 + l * 8);
                    al[c] = *(const bf16x8*)(Ar + (c * 2 + 1) * 512 + l * 8);
                }
#pragma unroll
                for (int c = 0; c < 3; c++)
#pragma unroll
                    for (int g = 0; g < 4; g++) { MFMA3(acc[g], wA[c][g][0], wA[c][g][1], ah[c], al[c]); }
            } else {
                bf16x8 ah[4], al[4];
#pragma unroll
                for (int c = 0; c < 4; c++) {
                    ah[c] = *(const bf16x8*)(Ar + ((3 + c) * 2) * 512 + l * 8);
                    al[c] = *(const bf16x8*)(Ar + ((3 + c) * 2 + 1) * 512 + l * 8);
                }
#pragma unroll
                for (int c = 0; c < 4; c++)
#pragma unroll
                    for (int g = 0; g < 4; g++) { MFMA3(acc[g], wA[c][g][0], wA[c][g][1], ah[c], al[c]); }
            }
            // lane-local cell update; h -> next buffer
#pragma unroll
            for (int r = 0; r < 4; r++) {
                float cc = sigm(acc[1][r]) * cst[r] + sigm(acc[0][r]) * tanhv(acc[2][r]);
                cst[r] = cc;
                float hh = sigm(acc[3][r]) * tanhv(cc);
                const int u = u0 + r;
                if (isL0) {
                    store_h(Aw, offC3(u, m), hh);        // layer1 input k=u
                    store_h(Aw, offC0(20 + u, m), hh);   // layer0 recurrent
                } else {
                    if (i < ENC) store_h(Aw, offC3(64 + u, m), hh);  // layer1 recurrent
                    else         store_h(Aw, offC0(20 + u, m), hh);  // decoder handoff
                }
            }
        }
        if (encX || decX0)
            store_h(Aw, offC0(kk, mm), (kk == 0) ? pre_f : emb_lookup(s_emb, kk, pre_i));
        __syncthreads();
    }

    // ============ decoder: waves 4-7 (they own c1) ============
    if (!isL0) {
#pragma unroll
        for (int c = 0; c < 3; c++)
#pragma unroll
            for (int g = 0; g < 4; g++)
#pragma unroll
                for (int s = 0; s < 2; s++)
                    wA[c][g][s] = *(const bf16x8*)(wsu + WDF +
                        ((c * 16 + (g * 4 + wl)) * 2 + s) * 512 + l * 8);
#pragma unroll
        for (int g = 0; g < 4; g++)
            biasv[g] = *(const f32x4*)(wsf + F_BD + g * 64 + u0);
    }

    for (int t = 0; t < DEC; ++t) {
        const ushort* Ar = Abuf[(t + 1) & 1];
        ushort* Aw = Abuf[t & 1];

        int pre_i = 0;
        const bool dX = (t + 1 < DEC) && bx && (kk >= 1);
        if (dX) pre_i = decoder_time[((b0g + mm) * DEC + (t + 1)) * 4 + sel];

        if (!isL0) {
            bf16x8 ah[3], al[3];
#pragma unroll
            for (int c = 0; c < 3; c++) {
                ah[c] = *(const bf16x8*)(Ar + (c * 2) * 512 + l * 8);
                al[c] = *(const bf16x8*)(Ar + (c * 2 + 1) * 512 + l * 8);
            }
            f32x4 acc[4];
#pragma unroll
            for (int g = 0; g < 4; g++) acc[g] = biasv[g];
#pragma unroll
            for (int c = 0; c < 3; c++)
#pragma unroll
                for (int g = 0; g < 4; g++) { MFMA3(acc[g], wA[c][g][0], wA[c][g][1], ah[c], al[c]); }
            f32x4 hv;
#pragma unroll
            for (int r = 0; r < 4; r++) {
                float cc = sigm(acc[1][r]) * cst[r] + sigm(acc[0][r]) * tanhv(acc[2][r]);
                cst[r] = cc;
                float hh = sigm(acc[3][r]) * tanhv(cc);
                store_h(Aw, offC0(20 + u0 + r, m), hh);  // recurrent for next step
                hv[r] = hh;
            }
            *(f32x4*)&sh1[m * 68 + u0] = hv;             // fp32 for output head
        }
        if (dX) store_h(Aw, offC0(kk, mm), emb_lookup(s_emb, kk, pre_i));
        __syncthreads();

        if (tid < 16) {
            float a = s_bout;
#pragma unroll 16
            for (int u = 0; u < 64; u++) a = fmaf(s_wout[u], sh1[tid * 68 + u], a);
            out[(b0g + tid) * DEC + t] = a;
            if (t + 1 < DEC) store_h(Aw, offC0(0, tid), a);  // autoregressive prev
        }
        __syncthreads();
    }
}

extern "C" void kernel_launch(void* const* d_in, const int* in_sizes, int n_in,
                              void* d_out, int out_size, void* d_ws, size_t ws_size,
                              hipStream_t stream)
{
    typedef const float* fp;
    const int* input_time   = (const int*)d_in[1];
    fp         label_p      = (fp)d_in[2];
    const int* decoder_time = (const int*)d_in[3];

    prep_kernel<<<128, 256, 0, stream>>>(
        (fp)d_in[4],  (fp)d_in[5],  (fp)d_in[6],  (fp)d_in[7],
        (fp)d_in[8],  (fp)d_in[9],  (fp)d_in[10], (fp)d_in[11],
        (fp)d_in[12], (fp)d_in[13], (fp)d_in[14], (fp)d_in[15],
        (fp)d_in[16], (fp)d_in[17],
        (fp)d_in[18], (fp)d_in[19], (fp)d_in[20], (fp)d_in[21],
        d_ws);

    lstm_mfma<<<NBLK, 512, 0, stream>>>(
        input_time, label_p, decoder_time, d_ws, (float*)d_out);
}

// Round 7
// 367.921 us; speedup vs baseline: 5.6579x; 1.1399x over previous
//
#include <hip/hip_runtime.h>

#define DEVFN __device__ __forceinline__

typedef float  f32x4  __attribute__((ext_vector_type(4)));
typedef short  bf16x8 __attribute__((ext_vector_type(8)));
typedef unsigned short u16x4 __attribute__((ext_vector_type(4)));

// Problem constants
constexpr int ENC = 168;
constexpr int DEC = 24;
constexpr int BT  = 16;            // batch tile (MFMA N)
constexpr int NBLK = 4096 / BT;    // 256 blocks -> 1 per CU

// Workspace layout. ushort region: bf16 weight fragments [c][tt16][lane64][j8]
constexpr int W0F = 0;             // 3*16*512 = 24576 ushorts (K=96: x20+h64+pad)
constexpr int W1F = 24576;         // 4*16*512 = 32768          (K=128: h0 + h1)
constexpr int WDF = 57344;         // 3*16*512 = 24576          (K=96: xin20+h64+pad)
// float region (float indices; ushort total 81920 = 163840 B = 40960 floats)
constexpr int F_B0   = 40960;
constexpr int F_B1   = 41216;
constexpr int F_BD   = 41472;
constexpr int F_WOUT = 41728;
constexpr int F_BOUT = 41792;
constexpr int F_EMB  = 41793;      // [574] hour120 wd24 mo52 woy378
constexpr int NEMB = 574;

DEVFN ushort f2bf(float v) {       // fp32 -> bf16 bits, RNE
    unsigned b = __float_as_uint(v);
    return (ushort)((b + 0x7FFFu + ((b >> 16) & 1u)) >> 16);
}
DEVFN float bf2f(ushort u) { return __uint_as_float(((unsigned)u) << 16); }
DEVFN float sigm(float x)  { return __builtin_amdgcn_rcpf(1.f + __expf(-x)); }
DEVFN float tanhv(float x) { return fmaf(2.f, sigm(x + x), -1.f); }

// ---------------- prep: weights -> bf16 MFMA fragments + fp32 tail ---------
// Fragment mapping (per 16-gate tile tt): gate row n = tt*16 + (l&15),
// k = c*32 + (l>>4)*8 + j. Used as MFMA A-operand (row = lane&15).
__global__ void prep_kernel(
    const float* __restrict__ w0ih, const float* __restrict__ w0hh,
    const float* __restrict__ b0ih, const float* __restrict__ b0hh,
    const float* __restrict__ w1ih, const float* __restrict__ w1hh,
    const float* __restrict__ b1ih, const float* __restrict__ b1hh,
    const float* __restrict__ wdih, const float* __restrict__ wdhh,
    const float* __restrict__ bdih, const float* __restrict__ bdhh,
    const float* __restrict__ wout, const float* __restrict__ boutp,
    const float* __restrict__ eh,   const float* __restrict__ ewd,
    const float* __restrict__ emo,  const float* __restrict__ ewoy,
    void* __restrict__ ws)
{
    ushort* wsu = (ushort*)ws;
    float*  wsf = (float*)ws;
    const int total = 81920 + 1407;
    for (int idx = blockIdx.x * blockDim.x + threadIdx.x; idx < total;
         idx += gridDim.x * blockDim.x) {
        if (idx < 81920) {
            int layer, q;
            if (idx < W1F)      { layer = 0; q = idx; }
            else if (idx < WDF) { layer = 1; q = idx - W1F; }
            else                { layer = 2; q = idx - WDF; }
            int c  = q >> 13;
            int tt = (q >> 9) & 15;
            int l  = (q >> 3) & 63;
            int j  = q & 7;
            int k  = c * 32 + (l >> 4) * 8 + j;
            int n  = tt * 16 + (l & 15);
            float v = 0.f;
            if (layer == 0) {
                if (k < 20) v = w0ih[n * 20 + k];
                else if (k < 84) v = w0hh[n * 64 + (k - 20)];
            } else if (layer == 1) {
                if (k < 64) v = w1ih[n * 64 + k];
                else        v = w1hh[n * 64 + (k - 64)];
            } else {
                if (k < 20) v = wdih[n * 20 + k];
                else if (k < 84) v = wdhh[n * 64 + (k - 20)];
            }
            wsu[idx] = f2bf(v);
        } else {
            int f = idx - 81920;
            float v;
            if (f < 256)      v = b0ih[f] + b0hh[f];
            else if (f < 512) v = b1ih[f - 256] + b1hh[f - 256];
            else if (f < 768) v = bdih[f - 512] + bdhh[f - 512];
            else if (f < 832) v = wout[f - 768];
            else if (f == 832) v = boutp[0];
            else {
                int e = f - 833;
                if (e < 120)      v = eh[e];
                else if (e < 144) v = ewd[e - 120];
                else if (e < 196) v = emo[e - 144];
                else              v = ewoy[e - 196];
            }
            wsf[40960 + f] = v;
        }
    }
}

DEVFN float emb_lookup(const float* s_emb, int kk, int idx) {
    int f = kk - 1;
    if (f < 5)  return s_emb[idx * 5 + f];
    if (f < 8)  return s_emb[120 + idx * 3 + (f - 5)];
    if (f < 12) return s_emb[144 + idx * 4 + (f - 8)];
    return s_emb[196 + idx * 7 + (f - 12)];
}

// activation-fragment offsets (ushort index; hi plane, lo plane at +512)
DEVFN int offC0(int k, int m) {            // chunks 0-2 space, k in [0,96)
    int c = k >> 5, k32 = k & 31;
    return (c * 2) * 512 + (m + 16 * (k32 >> 3)) * 8 + (k32 & 7);
}
DEVFN int offC3(int k, int m) {            // chunks 3-6 space, k in [0,128)
    int c = 3 + (k >> 5), k32 = k & 31;
    return (c * 2) * 512 + (m + 16 * (k32 >> 3)) * 8 + (k32 & 7);
}
DEVFN void store_h(ushort* A, int off, float h) {   // scalar (x-build only)
    ushort hi = f2bf(h);
    A[off]       = hi;
    A[off + 512] = f2bf(h - bf2f(hi));
}
// packed: 4 consecutive-k h values (k%4==0 base) -> one b64 per plane
DEVFN void store_h4(ushort* A, int off, const float* h) {
    u16x4 hi, lo;
#pragma unroll
    for (int r = 0; r < 4; r++) {
        hi[r] = f2bf(h[r]);
        lo[r] = f2bf(h[r] - bf2f(hi[r]));
    }
    *(u16x4*)(A + off)       = hi;
    *(u16x4*)(A + off + 512) = lo;
}

// scheme B: W_bf16 * (A_hi + A_lo), fp32 accumulate
#define MFMA2(ACC, W, AH, AL)                                              \
    ACC = __builtin_amdgcn_mfma_f32_16x16x32_bf16(W, AH, ACC, 0, 0, 0);    \
    ACC = __builtin_amdgcn_mfma_f32_16x16x32_bf16(W, AL, ACC, 0, 0, 0);

// ---------------- main persistent MFMA kernel: 512 thr ---------------------
// Waves 0-3: layer0 (encoder). Waves 4-7: layer1 (encoder) then decoder.
// Wave w computes gate tiles {gamma*4 + (w&3)}: lane (q,m) owns all 4 gates of
// units u0..u0+3 (u0=(w&3)*16+q*4) for batch m -> lane-local cell update.
__global__ __launch_bounds__(512)
__attribute__((amdgpu_waves_per_eu(2, 2)))
void lstm_mfma(
    const int* __restrict__ input_time, const float* __restrict__ label_p,
    const int* __restrict__ decoder_time, const void* __restrict__ ws,
    float* __restrict__ out)
{
    const ushort* wsu = (const ushort*)ws;
    const float*  wsf = (const float*)ws;

    // double-buffered activation fragments: 7 chunks x hi/lo x 512 ushorts
    __shared__ __align__(16) ushort Abuf[2][7 * 2 * 512];
    __shared__ float s_emb[NEMB];
    __shared__ float s_wout[64];
    __shared__ float sh1[16 * 68];     // [m][u] padded
    __shared__ float s_bout;

    const int tid = threadIdx.x;
    const int w   = tid >> 6;          // wave 0..7
    const int l   = tid & 63;
    const int q   = l >> 4;
    const int m   = l & 15;
    const int wl  = w & 3;
    const bool isL0 = (w < 4);
    const int b0g = blockIdx.x * BT;
    const int u0  = wl * 16 + q * 4;   // this lane's 4 units

    // ---- init ----
    for (int i = tid; i < 2 * 7 * 2 * 512; i += 512) ((ushort*)Abuf)[i] = 0;
    for (int i = tid; i < NEMB; i += 512) s_emb[i] = wsf[F_EMB + i];
    if (tid < 64) s_wout[tid] = wsf[F_WOUT + tid];
    if (tid == 0) s_bout = wsf[F_BOUT];

    // ---- weight fragments (A-operand, bf16 hi only), persistent ----
    bf16x8 wA[4][4];                   // [chunk][gamma]; L0 uses [0..2][*]
    if (isL0) {
#pragma unroll
        for (int c = 0; c < 3; c++)
#pragma unroll
            for (int g = 0; g < 4; g++)
                wA[c][g] = *(const bf16x8*)(wsu + W0F +
                    (c * 16 + g * 4 + wl) * 512 + l * 8);
    } else {
#pragma unroll
        for (int c = 0; c < 4; c++)
#pragma unroll
            for (int g = 0; g < 4; g++)
                wA[c][g] = *(const bf16x8*)(wsu + W1F +
                    (c * 16 + g * 4 + wl) * 512 + l * 8);
    }
    f32x4 biasv[4];
#pragma unroll
    for (int g = 0; g < 4; g++)
        biasv[g] = *(const f32x4*)(wsf + (isL0 ? F_B0 : F_B1) + g * 64 + u0);

    float cst[4] = {0.f, 0.f, 0.f, 0.f};

    // x-build roles: 320 threads = 20 features x 16 batches
    const int kk = tid >> 4, mm = tid & 15;
    const bool bx = (tid < 320);
    const int sel = (kk <= 5) ? 0 : (kk <= 8) ? 1 : (kk <= 12) ? 2 : 3;

    __syncthreads();
    if (bx) {    // x(0) into Abuf[0]
        float v = (kk == 0) ? label_p[(b0g + mm) * ENC]
                : emb_lookup(s_emb, kk, input_time[((b0g + mm) * ENC) * 4 + sel]);
        store_h(Abuf[0], offC0(kk, mm), v);
    }
    __syncthreads();

    // ============ encoder pipeline: iter i = layer0(i) + layer1(i-1) ========
    for (int i = 0; i <= ENC; ++i) {
        const ushort* Ar = Abuf[i & 1];
        ushort* Aw = Abuf[(i + 1) & 1];
        const bool active = isL0 ? (i < ENC) : (i >= 1);

        // prefetch globals for next x
        float pre_f = 0.f; int pre_i = 0;
        const bool encX  = (i + 1 < ENC) && bx;
        const bool decX0 = (i == ENC) && bx;
        if (encX) {
            if (kk == 0) pre_f = label_p[(b0g + mm) * ENC + (i + 1)];
            else         pre_i = input_time[((b0g + mm) * ENC + (i + 1)) * 4 + sel];
        } else if (decX0) {
            if (kk == 0) pre_f = label_p[(b0g + mm) * ENC + (ENC - 1)];
            else         pre_i = decoder_time[((b0g + mm) * DEC) * 4 + sel];
        }

        if (active) {
            f32x4 acc[4];
#pragma unroll
            for (int g = 0; g < 4; g++) acc[g] = biasv[g];
            if (isL0) {
                bf16x8 ah[3], al[3];
#pragma unroll
                for (int c = 0; c < 3; c++) {
                    ah[c] = *(const bf16x8*)(Ar + (c * 2) * 512 + l * 8);
                    al[c] = *(const bf16x8*)(Ar + (c * 2 + 1) * 512 + l * 8);
                }
#pragma unroll
                for (int c = 0; c < 3; c++)
#pragma unroll
                    for (int g = 0; g < 4; g++) { MFMA2(acc[g], wA[c][g], ah[c], al[c]); }
            } else {
                bf16x8 ah[4], al[4];
#pragma unroll
                for (int c = 0; c < 4; c++) {
                    ah[c] = *(const bf16x8*)(Ar + ((3 + c) * 2) * 512 + l * 8);
                    al[c] = *(const bf16x8*)(Ar + ((3 + c) * 2 + 1) * 512 + l * 8);
                }
#pragma unroll
                for (int c = 0; c < 4; c++)
#pragma unroll
                    for (int g = 0; g < 4; g++) { MFMA2(acc[g], wA[c][g], ah[c], al[c]); }
            }
            // lane-local cell update; h -> next buffer (packed quad stores)
            float hv[4];
#pragma unroll
            for (int r = 0; r < 4; r++) {
                float cc = sigm(acc[1][r]) * cst[r] + sigm(acc[0][r]) * tanhv(acc[2][r]);
                cst[r] = cc;
                hv[r] = sigm(acc[3][r]) * tanhv(cc);
            }
            if (isL0) {
                store_h4(Aw, offC3(u0, m), hv);         // layer1 input k=u
                store_h4(Aw, offC0(20 + u0, m), hv);    // layer0 recurrent
            } else {
                if (i < ENC) store_h4(Aw, offC3(64 + u0, m), hv);  // l1 recurrent
                else         store_h4(Aw, offC0(20 + u0, m), hv);  // dec handoff
            }
        }
        if (encX || decX0)
            store_h(Aw, offC0(kk, mm), (kk == 0) ? pre_f : emb_lookup(s_emb, kk, pre_i));
        __syncthreads();
    }

    // ============ decoder: waves 4-7 (they own c1) ============
    if (!isL0) {
#pragma unroll
        for (int c = 0; c < 3; c++)
#pragma unroll
            for (int g = 0; g < 4; g++)
                wA[c][g] = *(const bf16x8*)(wsu + WDF +
                    (c * 16 + g * 4 + wl) * 512 + l * 8);
#pragma unroll
        for (int g = 0; g < 4; g++)
            biasv[g] = *(const f32x4*)(wsf + F_BD + g * 64 + u0);
    }

    for (int t = 0; t < DEC; ++t) {
        const ushort* Ar = Abuf[(t + 1) & 1];
        ushort* Aw = Abuf[t & 1];

        int pre_i = 0;
        const bool dX = (t + 1 < DEC) && bx && (kk >= 1);
        if (dX) pre_i = decoder_time[((b0g + mm) * DEC + (t + 1)) * 4 + sel];

        if (!isL0) {
            bf16x8 ah[3], al[3];
#pragma unroll
            for (int c = 0; c < 3; c++) {
                ah[c] = *(const bf16x8*)(Ar + (c * 2) * 512 + l * 8);
                al[c] = *(const bf16x8*)(Ar + (c * 2 + 1) * 512 + l * 8);
            }
            f32x4 acc[4];
#pragma unroll
            for (int g = 0; g < 4; g++) acc[g] = biasv[g];
#pragma unroll
            for (int c = 0; c < 3; c++)
#pragma unroll
                for (int g = 0; g < 4; g++) { MFMA2(acc[g], wA[c][g], ah[c], al[c]); }
            float hv[4];
#pragma unroll
            for (int r = 0; r < 4; r++) {
                float cc = sigm(acc[1][r]) * cst[r] + sigm(acc[0][r]) * tanhv(acc[2][r]);
                cst[r] = cc;
                hv[r] = sigm(acc[3][r]) * tanhv(cc);
            }
            store_h4(Aw, offC0(20 + u0, m), hv);        // recurrent for next step
            *(f32x4*)&sh1[m * 68 + u0] = *(f32x4*)hv;   // fp32 for output head
        }
        if (dX) store_h(Aw, offC0(kk, mm), emb_lookup(s_emb, kk, pre_i));
        __syncthreads();

        if (tid < 16) {
            float a = s_bout;
#pragma unroll 16
            for (int u = 0; u < 64; u++) a = fmaf(s_wout[u], sh1[tid * 68 + u], a);
            out[(b0g + tid) * DEC + t] = a;
            if (t + 1 < DEC) store_h(Aw, offC0(0, tid), a);  // autoregressive prev
        }
        __syncthreads();
    }
}

extern "C" void kernel_launch(void* const* d_in, const int* in_sizes, int n_in,
                              void* d_out, int out_size, void* d_ws, size_t ws_size,
                              hipStream_t stream)
{
    typedef const float* fp;
    const int* input_time   = (const int*)d_in[1];
    fp         label_p      = (fp)d_in[2];
    const int* decoder_time = (const int*)d_in[3];

    prep_kernel<<<128, 256, 0, stream>>>(
        (fp)d_in[4],  (fp)d_in[5],  (fp)d_in[6],  (fp)d_in[7],
        (fp)d_in[8],  (fp)d_in[9],  (fp)d_in[10], (fp)d_in[11],
        (fp)d_in[12], (fp)d_in[13], (fp)d_in[14], (fp)d_in[15],
        (fp)d_in[16], (fp)d_in[17],
        (fp)d_in[18], (fp)d_in[19], (fp)d_in[20], (fp)d_in[21],
        d_ws);

    lstm_mfma<<<NBLK, 512, 0, stream>>>(
        input_time, label_p, decoder_time, d_ws, (float*)d_out);
}

// Round 8
// 355.438 us; speedup vs baseline: 5.8566x; 1.0351x over previous
//
#include <hip/hip_runtime.h>

#define DEVFN __device__ __forceinline__

typedef float  f32x4  __attribute__((ext_vector_type(4)));
typedef short  bf16x8 __attribute__((ext_vector_type(8)));
typedef unsigned short u16x4 __attribute__((ext_vector_type(4)));

// Problem constants
constexpr int ENC = 168;
constexpr int DEC = 24;
constexpr int BT  = 16;            // batch tile (MFMA N)
constexpr int NBLK = 4096 / BT;    // 256 blocks -> 1 per CU

// Workspace layout. ushort region: bf16 weight fragments [c][tt16][lane64][j8]
constexpr int W0F = 0;             // 3*16*512 = 24576 ushorts (K=96: x20+h64+pad)
constexpr int W1F = 24576;         // 4*16*512 = 32768          (K=128: h0 + h1)
constexpr int WDF = 57344;         // 3*16*512 = 24576          (K=96: xin20+h64+pad)
// float region (float indices; ushort total 81920 = 163840 B = 40960 floats)
constexpr int F_B0   = 40960;
constexpr int F_B1   = 41216;
constexpr int F_BD   = 41472;
constexpr int F_WOUT = 41728;
constexpr int F_BOUT = 41792;
constexpr int F_EMB  = 41793;      // [574] hour120 wd24 mo52 woy378
constexpr int NEMB = 574;

DEVFN ushort f2bf(float v) {       // fp32 -> bf16 bits, RNE
    unsigned b = __float_as_uint(v);
    return (ushort)((b + 0x7FFFu + ((b >> 16) & 1u)) >> 16);
}
DEVFN float bf2f(ushort u) { return __uint_as_float(((unsigned)u) << 16); }
DEVFN float sigm(float x)  { return __builtin_amdgcn_rcpf(1.f + __expf(-x)); }
DEVFN float tanhv(float x) { return fmaf(2.f, sigm(x + x), -1.f); }

// pin a value into VGPRs: the empty asm consumes+redefines it, making
// rematerialization of the originating load illegal for the compiler.
DEVFN void pinv(bf16x8& v) { asm volatile("" : "+v"(v)); }
DEVFN void pinf(f32x4& v)  { asm volatile("" : "+v"(v)); }

// ---------------- prep: weights -> bf16 MFMA fragments + fp32 tail ---------
// Fragment mapping (per 16-gate tile tt): gate row n = tt*16 + (l&15),
// k = c*32 + (l>>4)*8 + j. Used as MFMA A-operand (row = lane&15).
__global__ void prep_kernel(
    const float* __restrict__ w0ih, const float* __restrict__ w0hh,
    const float* __restrict__ b0ih, const float* __restrict__ b0hh,
    const float* __restrict__ w1ih, const float* __restrict__ w1hh,
    const float* __restrict__ b1ih, const float* __restrict__ b1hh,
    const float* __restrict__ wdih, const float* __restrict__ wdhh,
    const float* __restrict__ bdih, const float* __restrict__ bdhh,
    const float* __restrict__ wout, const float* __restrict__ boutp,
    const float* __restrict__ eh,   const float* __restrict__ ewd,
    const float* __restrict__ emo,  const float* __restrict__ ewoy,
    void* __restrict__ ws)
{
    ushort* wsu = (ushort*)ws;
    float*  wsf = (float*)ws;
    const int total = 81920 + 1407;
    for (int idx = blockIdx.x * blockDim.x + threadIdx.x; idx < total;
         idx += gridDim.x * blockDim.x) {
        if (idx < 81920) {
            int layer, q;
            if (idx < W1F)      { layer = 0; q = idx; }
            else if (idx < WDF) { layer = 1; q = idx - W1F; }
            else                { layer = 2; q = idx - WDF; }
            int c  = q >> 13;
            int tt = (q >> 9) & 15;
            int l  = (q >> 3) & 63;
            int j  = q & 7;
            int k  = c * 32 + (l >> 4) * 8 + j;
            int n  = tt * 16 + (l & 15);
            float v = 0.f;
            if (layer == 0) {
                if (k < 20) v = w0ih[n * 20 + k];
                else if (k < 84) v = w0hh[n * 64 + (k - 20)];
            } else if (layer == 1) {
                if (k < 64) v = w1ih[n * 64 + k];
                else        v = w1hh[n * 64 + (k - 64)];
            } else {
                if (k < 20) v = wdih[n * 20 + k];
                else if (k < 84) v = wdhh[n * 64 + (k - 20)];
            }
            wsu[idx] = f2bf(v);
        } else {
            int f = idx - 81920;
            float v;
            if (f < 256)      v = b0ih[f] + b0hh[f];
            else if (f < 512) v = b1ih[f - 256] + b1hh[f - 256];
            else if (f < 768) v = bdih[f - 512] + bdhh[f - 512];
            else if (f < 832) v = wout[f - 768];
            else if (f == 832) v = boutp[0];
            else {
                int e = f - 833;
                if (e < 120)      v = eh[e];
                else if (e < 144) v = ewd[e - 120];
                else if (e < 196) v = emo[e - 144];
                else              v = ewoy[e - 196];
            }
            wsf[40960 + f] = v;
        }
    }
}

DEVFN float emb_lookup(const float* s_emb, int kk, int idx) {
    int f = kk - 1;
    if (f < 5)  return s_emb[idx * 5 + f];
    if (f < 8)  return s_emb[120 + idx * 3 + (f - 5)];
    if (f < 12) return s_emb[144 + idx * 4 + (f - 8)];
    return s_emb[196 + idx * 7 + (f - 12)];
}

// activation-fragment offsets (ushort index; hi plane, lo plane at +512)
DEVFN int offC0(int k, int m) {            // chunks 0-2 space, k in [0,96)
    int c = k >> 5, k32 = k & 31;
    return (c * 2) * 512 + (m + 16 * (k32 >> 3)) * 8 + (k32 & 7);
}
DEVFN int offC3(int k, int m) {            // chunks 3-6 space, k in [0,128)
    int c = 3 + (k >> 5), k32 = k & 31;
    return (c * 2) * 512 + (m + 16 * (k32 >> 3)) * 8 + (k32 & 7);
}
DEVFN void store_h(ushort* A, int off, float h) {   // scalar (x-build only)
    ushort hi = f2bf(h);
    A[off]       = hi;
    A[off + 512] = f2bf(h - bf2f(hi));
}
// packed: 4 consecutive-k h values (k%4==0 base) -> one b64 per plane
DEVFN void store_h4(ushort* A, int off, const float* h) {
    u16x4 hi, lo;
#pragma unroll
    for (int r = 0; r < 4; r++) {
        hi[r] = f2bf(h[r]);
        lo[r] = f2bf(h[r] - bf2f(hi[r]));
    }
    *(u16x4*)(A + off)       = hi;
    *(u16x4*)(A + off + 512) = lo;
}

// scheme B: W_bf16 * (A_hi + A_lo), fp32 accumulate
#define MFMA2(ACC, W, AH, AL)                                              \
    ACC = __builtin_amdgcn_mfma_f32_16x16x32_bf16(W, AH, ACC, 0, 0, 0);    \
    ACC = __builtin_amdgcn_mfma_f32_16x16x32_bf16(W, AL, ACC, 0, 0, 0);

// ---------------- main persistent MFMA kernel: 512 thr ---------------------
// Waves 0-3: layer0 (encoder). Waves 4-7: layer1 (encoder) then decoder.
// Wave w computes gate tiles {gamma*4 + (w&3)}: lane (q,m) owns all 4 gates of
// units u0..u0+3 (u0=(w&3)*16+q*4) for batch m -> lane-local cell update.
__global__ __launch_bounds__(512)
__attribute__((amdgpu_waves_per_eu(2, 2)))
void lstm_mfma(
    const int* __restrict__ input_time, const float* __restrict__ label_p,
    const int* __restrict__ decoder_time, const void* __restrict__ ws,
    float* __restrict__ out)
{
    const ushort* wsu = (const ushort*)ws;
    const float*  wsf = (const float*)ws;

    // double-buffered activation fragments: 7 chunks x hi/lo x 512 ushorts
    __shared__ __align__(16) ushort Abuf[2][7 * 2 * 512];
    __shared__ float s_emb[NEMB];
    __shared__ float s_wout[64];
    __shared__ float sh1[16 * 68];     // [m][u] padded
    __shared__ float s_bout;

    const int tid = threadIdx.x;
    const int w   = tid >> 6;          // wave 0..7
    const int l   = tid & 63;
    const int q   = l >> 4;
    const int m   = l & 15;
    const int wl  = w & 3;
    const bool isL0 = (w < 4);
    const int b0g = blockIdx.x * BT;
    const int u0  = wl * 16 + q * 4;   // this lane's 4 units

    // ---- init ----
    for (int i = tid; i < 2 * 7 * 2 * 512; i += 512) ((ushort*)Abuf)[i] = 0;
    for (int i = tid; i < NEMB; i += 512) s_emb[i] = wsf[F_EMB + i];
    if (tid < 64) s_wout[tid] = wsf[F_WOUT + tid];
    if (tid == 0) s_bout = wsf[F_BOUT];

    // ---- weight fragments (A-operand, bf16), pinned register-resident ----
    bf16x8 wA[4][4];                   // [chunk][gamma]; L0 uses [0..2][*]
    if (isL0) {
#pragma unroll
        for (int c = 0; c < 3; c++)
#pragma unroll
            for (int g = 0; g < 4; g++)
                wA[c][g] = *(const bf16x8*)(wsu + W0F +
                    (c * 16 + g * 4 + wl) * 512 + l * 8);
        wA[3][0] = wA[3][1] = wA[3][2] = wA[3][3] = bf16x8{0,0,0,0,0,0,0,0};
    } else {
#pragma unroll
        for (int c = 0; c < 4; c++)
#pragma unroll
            for (int g = 0; g < 4; g++)
                wA[c][g] = *(const bf16x8*)(wsu + W1F +
                    (c * 16 + g * 4 + wl) * 512 + l * 8);
    }
#pragma unroll
    for (int c = 0; c < 4; c++)
#pragma unroll
        for (int g = 0; g < 4; g++) pinv(wA[c][g]);

    f32x4 biasv[4];
#pragma unroll
    for (int g = 0; g < 4; g++) {
        biasv[g] = *(const f32x4*)(wsf + (isL0 ? F_B0 : F_B1) + g * 64 + u0);
        pinf(biasv[g]);
    }

    float cst[4] = {0.f, 0.f, 0.f, 0.f};

    // x-build roles: 320 threads = 20 features x 16 batches
    const int kk = tid >> 4, mm = tid & 15;
    const bool bx = (tid < 320);
    const int sel = (kk <= 5) ? 0 : (kk <= 8) ? 1 : (kk <= 12) ? 2 : 3;

    __syncthreads();
    if (bx) {    // x(0) into Abuf[0]
        float v = (kk == 0) ? label_p[(b0g + mm) * ENC]
                : emb_lookup(s_emb, kk, input_time[((b0g + mm) * ENC) * 4 + sel]);
        store_h(Abuf[0], offC0(kk, mm), v);
    }
    __syncthreads();

    // ============ encoder pipeline: iter i = layer0(i) + layer1(i-1) ========
    for (int i = 0; i <= ENC; ++i) {
        const ushort* Ar = Abuf[i & 1];
        ushort* Aw = Abuf[(i + 1) & 1];
        const bool active = isL0 ? (i < ENC) : (i >= 1);

        // prefetch globals for next x
        float pre_f = 0.f; int pre_i = 0;
        const bool encX  = (i + 1 < ENC) && bx;
        const bool decX0 = (i == ENC) && bx;
        if (encX) {
            if (kk == 0) pre_f = label_p[(b0g + mm) * ENC + (i + 1)];
            else         pre_i = input_time[((b0g + mm) * ENC + (i + 1)) * 4 + sel];
        } else if (decX0) {
            if (kk == 0) pre_f = label_p[(b0g + mm) * ENC + (ENC - 1)];
            else         pre_i = decoder_time[((b0g + mm) * DEC) * 4 + sel];
        }

        if (active) {
            f32x4 acc[4];
#pragma unroll
            for (int g = 0; g < 4; g++) acc[g] = biasv[g];
            if (isL0) {
                bf16x8 ah[3], al[3];
#pragma unroll
                for (int c = 0; c < 3; c++) {
                    ah[c] = *(const bf16x8*)(Ar + (c * 2) * 512 + l * 8);
                    al[c] = *(const bf16x8*)(Ar + (c * 2 + 1) * 512 + l * 8);
                }
#pragma unroll
                for (int c = 0; c < 3; c++)
#pragma unroll
                    for (int g = 0; g < 4; g++) { MFMA2(acc[g], wA[c][g], ah[c], al[c]); }
            } else {
                bf16x8 ah[4], al[4];
#pragma unroll
                for (int c = 0; c < 4; c++) {
                    ah[c] = *(const bf16x8*)(Ar + ((3 + c) * 2) * 512 + l * 8);
                    al[c] = *(const bf16x8*)(Ar + ((3 + c) * 2 + 1) * 512 + l * 8);
                }
#pragma unroll
                for (int c = 0; c < 4; c++)
#pragma unroll
                    for (int g = 0; g < 4; g++) { MFMA2(acc[g], wA[c][g], ah[c], al[c]); }
            }
            // lane-local cell update; h -> next buffer (packed quad stores)
            float hv[4];
#pragma unroll
            for (int r = 0; r < 4; r++) {
                float cc = sigm(acc[1][r]) * cst[r] + sigm(acc[0][r]) * tanhv(acc[2][r]);
                cst[r] = cc;
                hv[r] = sigm(acc[3][r]) * tanhv(cc);
            }
            if (isL0) {
                store_h4(Aw, offC3(u0, m), hv);         // layer1 input k=u
                store_h4(Aw, offC0(20 + u0, m), hv);    // layer0 recurrent
            } else {
                if (i < ENC) store_h4(Aw, offC3(64 + u0, m), hv);  // l1 recurrent
                else         store_h4(Aw, offC0(20 + u0, m), hv);  // dec handoff
            }
        }
        if (encX || decX0)
            store_h(Aw, offC0(kk, mm), (kk == 0) ? pre_f : emb_lookup(s_emb, kk, pre_i));
        __syncthreads();
    }

    // ============ decoder: waves 4-7 (they own c1) ============
    if (!isL0) {
#pragma unroll
        for (int c = 0; c < 3; c++)
#pragma unroll
            for (int g = 0; g < 4; g++)
                wA[c][g] = *(const bf16x8*)(wsu + WDF +
                    (c * 16 + g * 4 + wl) * 512 + l * 8);
#pragma unroll
        for (int c = 0; c < 3; c++)
#pragma unroll
            for (int g = 0; g < 4; g++) pinv(wA[c][g]);
#pragma unroll
        for (int g = 0; g < 4; g++) {
            biasv[g] = *(const f32x4*)(wsf + F_BD + g * 64 + u0);
            pinf(biasv[g]);
        }
    }

    for (int t = 0; t < DEC; ++t) {
        const ushort* Ar = Abuf[(t + 1) & 1];
        ushort* Aw = Abuf[t & 1];

        int pre_i = 0;
        const bool dX = (t + 1 < DEC) && bx && (kk >= 1);
        if (dX) pre_i = decoder_time[((b0g + mm) * DEC + (t + 1)) * 4 + sel];

        if (!isL0) {
            bf16x8 ah[3], al[3];
#pragma unroll
            for (int c = 0; c < 3; c++) {
                ah[c] = *(const bf16x8*)(Ar + (c * 2) * 512 + l * 8);
                al[c] = *(const bf16x8*)(Ar + (c * 2 + 1) * 512 + l * 8);
            }
            f32x4 acc[4];
#pragma unroll
            for (int g = 0; g < 4; g++) acc[g] = biasv[g];
#pragma unroll
            for (int c = 0; c < 3; c++)
#pragma unroll
                for (int g = 0; g < 4; g++) { MFMA2(acc[g], wA[c][g], ah[c], al[c]); }
            float hv[4];
#pragma unroll
            for (int r = 0; r < 4; r++) {
                float cc = sigm(acc[1][r]) * cst[r] + sigm(acc[0][r]) * tanhv(acc[2][r]);
                cst[r] = cc;
                hv[r] = sigm(acc[3][r]) * tanhv(cc);
            }
            store_h4(Aw, offC0(20 + u0, m), hv);        // recurrent for next step
            *(f32x4*)&sh1[m * 68 + u0] = *(f32x4*)hv;   // fp32 for output head
        }
        if (dX) store_h(Aw, offC0(kk, mm), emb_lookup(s_emb, kk, pre_i));
        __syncthreads();

        if (tid < 16) {
            float a = s_bout;
#pragma unroll 16
            for (int u = 0; u < 64; u++) a = fmaf(s_wout[u], sh1[tid * 68 + u], a);
            out[(b0g + tid) * DEC + t] = a;
            if (t + 1 < DEC) store_h(Aw, offC0(0, tid), a);  // autoregressive prev
        }
        __syncthreads();
    }
}

extern "C" void kernel_launch(void* const* d_in, const int* in_sizes, int n_in,
                              void* d_out, int out_size, void* d_ws, size_t ws_size,
                              hipStream_t stream)
{
    typedef const float* fp;
    const int* input_time   = (const int*)d_in[1];
    fp         label_p      = (fp)d_in[2];
    const int* decoder_time = (const int*)d_in[3];

    prep_kernel<<<128, 256, 0, stream>>>(
        (fp)d_in[4],  (fp)d_in[5],  (fp)d_in[6],  (fp)d_in[7],
        (fp)d_in[8],  (fp)d_in[9],  (fp)d_in[10], (fp)d_in[11],
        (fp)d_in[12], (fp)d_in[13], (fp)d_in[14], (fp)d_in[15],
        (fp)d_in[16], (fp)d_in[17],
        (fp)d_in[18], (fp)d_in[19], (fp)d_in[20], (fp)d_in[21],
        d_ws);

    lstm_mfma<<<NBLK, 512, 0, stream>>>(
        input_time, label_p, decoder_time, d_ws, (float*)d_out);
}